// Round 1
// baseline (154.735 us; speedup 1.0000x reference)
//
#include <hip/hip_runtime.h>
#include <math.h>

#define TT 16
#define CC 2048
#define NEGV -1.0e30f

__global__ __launch_bounds__(256) void cpa_kernel(
    const float* __restrict__ f1, const float* __restrict__ f2,
    float* __restrict__ out, int B)
{
    const int b   = blockIdx.x;
    const int tid = threadIdx.x;
    const int i   = tid >> 4;
    const int j   = tid & 15;

    __shared__ float2 PD[TT][TT];   // .x = pred (after 2D cumsum), .y = D
    __shared__ float  fin[TT];

    // ---------------- scores GEMM: scores[i][j] = f1[b,i,:] . f2[b,j,:] ----------------
    const float4* A4 = reinterpret_cast<const float4*>(f1 + (size_t)b * TT * CC) + i * (CC / 4);
    const float4* B4 = reinterpret_cast<const float4*>(f2 + (size_t)b * TT * CC) + j * (CC / 4);
    float acc = 0.0f;
    #pragma unroll 8
    for (int t = 0; t < CC / 4; ++t) {
        float4 x = A4[t];
        float4 y = B4[t];
        acc = fmaf(x.x, y.x, acc);
        acc = fmaf(x.y, y.y, acc);
        acc = fmaf(x.z, y.z, acc);
        acc = fmaf(x.w, y.w, acc);
    }
    const float score = acc * (1.0f / sqrtf((float)CC));

    // ---------------- softmax over j (16-lane row groups, xor butterfly) ----------------
    float mx = score;
    #pragma unroll
    for (int d = 1; d < 16; d <<= 1) mx = fmaxf(mx, __shfl_xor(mx, d));
    const float e = expf(score - mx);
    float sm = e;
    #pragma unroll
    for (int d = 1; d < 16; d <<= 1) sm += __shfl_xor(sm, d);
    const float pred = e / sm;

    PD[i][j].x = pred;
    __syncthreads();

    // cumsum over axis -2 (rows, per column), then axis -1 (cols, per row); serial = numpy order
    if (tid < TT) {
        float run = 0.0f;
        for (int r = 0; r < TT; ++r) { run += PD[r][tid].x; PD[r][tid].x = run; }
    }
    __syncthreads();
    if (tid < TT) {
        float run = 0.0f;
        for (int c = 0; c < TT; ++c) { run += PD[tid][c].x; PD[tid][c].x = run; }
    }
    __syncthreads();

    // ---------------- per-thread step-invariant precompute ----------------
    const float pij = PD[i][j].x;
    float cb[TT], rj[TT], ca[TT], ra[TT];
    #pragma unroll
    for (int bb = 0; bb < TT; ++bb) {
        cb[bb] = pij - PD[i][bb].x + (bb < j ? 0.0f : NEGV);
        int d2 = j - bb; if (d2 < 1) d2 = 1;
        rj[bb] = rsqrtf((float)d2);
    }
    #pragma unroll
    for (int a = 0; a < TT; ++a) {
        ca[a] = -PD[a][j].x + (a < i ? 0.0f : NEGV);
        int d1 = i - a; if (d1 < 1) d1 = 1;
        ra[a] = rsqrtf((float)d1);
    }

    // D0 = pred / ((i+1)*(j+1))
    const float D0 = pij / (float)((i + 1) * (j + 1));
    PD[i][j].y = D0;
    if (tid == 255) fin[0] = D0;
    __syncthreads();

    // ---------------- DP: 15 sequential steps ----------------
    for (int k = 1; k < TT; ++k) {
        float m = -3.0e38f;
        #pragma unroll
        for (int a = 0; a < TT; ++a) {
            #pragma unroll
            for (int bb = 0; bb < TT; ++bb) {
                float2 pd = PD[a][bb];                      // broadcast ds_read_b64
                float s2 = ca[a] + cb[bb] + pd.x;           // pij - P[i,bb] - P[a,j] + P[a,bb] (+pen)
                float r  = ra[a] * rj[bb];                  // 1/sqrt((i-a)*(j-bb))
                m = fmaxf(m, fmaf(s2, r, pd.y));            // + D_prev[a,bb]
            }
        }
        __syncthreads();
        PD[i][j].y = m;
        if (tid == 255) fin[k] = m;
        __syncthreads();
    }

    // ---------------- final: loss = -max_k fin[k], step = first argmax ----------------
    if (tid == 0) {
        float best = fin[0];
        int   idx  = 0;
        #pragma unroll
        for (int k = 1; k < TT; ++k) {
            if (fin[k] > best) { best = fin[k]; idx = k; }
        }
        out[b]     = -best;
        out[B + b] = (float)idx;
    }
}

extern "C" void kernel_launch(void* const* d_in, const int* in_sizes, int n_in,
                              void* d_out, int out_size, void* d_ws, size_t ws_size,
                              hipStream_t stream)
{
    const float* f1 = (const float*)d_in[0];
    const float* f2 = (const float*)d_in[1];
    float* out = (float*)d_out;
    const int B = in_sizes[0] / (TT * CC);   // 256
    hipLaunchKernelGGL(cpa_kernel, dim3(B), dim3(256), 0, stream, f1, f2, out, B);
}

// Round 2
// 36.910 us; speedup vs baseline: 4.1923x; 4.1923x over previous
//
#include <hip/hip_runtime.h>
#include <math.h>

#define TT 16
#define CC 2048
#define NEGV -1.0e30f
#define CW 256              // GEMM chunk width (floats)
#define NCK (CC / CW)       // 8 chunks
#define ASTR 260            // A/B LDS row stride (floats), 16B-aligned + bank-fair
#define PSTR 17
#define DSTR 20             // 80B row stride: 16B-aligned for b128 reads

__global__ __launch_bounds__(1024) void cpa_kernel(
    const float* __restrict__ f1, const float* __restrict__ f2,
    float* __restrict__ out, int B)
{
    __shared__ float As[TT * ASTR];
    __shared__ float Bs[TT * ASTR];
    __shared__ float part[4 * TT * PSTR];
    __shared__ float Pm[TT * PSTR];
    __shared__ float Dm[2 * TT * DSTR];
    __shared__ float fin[TT];

    const int b   = blockIdx.x;
    const int tid = threadIdx.x;

    // ================= GEMM: scores = f1 . f2^T (per batch) =================
    // compute decomposition: thread = (ig, ksHi, ksLo, j); wave = fixed (ig,ksHi)
    const int ig   = tid >> 8;          // 0..3  -> rows 4*ig..4*ig+3
    const int rem  = tid & 255;
    const int ksHi = rem >> 6;          // 0..3
    const int ksLo = (rem >> 4) & 3;    // 0..3
    const int jg   = rem & 15;          // output col j
    const int ks   = ksHi * 4 + ksLo;   // 0..15: 16-float K-slice within chunk

    const float* baseA = f1 + (size_t)b * TT * CC;
    const float* baseB = f2 + (size_t)b * TT * CC;
    const int lrow = tid >> 6;          // staging: row 0..15
    const int lc4  = tid & 63;          // staging: float4 col 0..63

    float acc[4] = {0.f, 0.f, 0.f, 0.f};

    float4 av = *(const float4*)(baseA + lrow * CC + lc4 * 4);
    float4 bv = *(const float4*)(baseB + lrow * CC + lc4 * 4);

    for (int ck = 0; ck < NCK; ++ck) {
        *(float4*)(&As[lrow * ASTR + lc4 * 4]) = av;
        *(float4*)(&Bs[lrow * ASTR + lc4 * 4]) = bv;
        __syncthreads();
        if (ck + 1 < NCK) {   // prefetch next chunk; wait lands at next write
            av = *(const float4*)(baseA + lrow * CC + (ck + 1) * CW + lc4 * 4);
            bv = *(const float4*)(baseB + lrow * CC + (ck + 1) * CW + lc4 * 4);
        }
        const int ko = ks * 16;
        #pragma unroll
        for (int t = 0; t < 4; ++t) {
            float4 vb = *(const float4*)(&Bs[jg * ASTR + ko + t * 4]);
            #pragma unroll
            for (int m = 0; m < 4; ++m) {
                float4 va = *(const float4*)(&As[(ig * 4 + m) * ASTR + ko + t * 4]);
                acc[m] = fmaf(va.x, vb.x, acc[m]);
                acc[m] = fmaf(va.y, vb.y, acc[m]);
                acc[m] = fmaf(va.z, vb.z, acc[m]);
                acc[m] = fmaf(va.w, vb.w, acc[m]);
            }
        }
        __syncthreads();
    }
    // reduce over ksLo (lane bits 4,5), then stash per-ksHi partials
    #pragma unroll
    for (int m = 0; m < 4; ++m) {
        acc[m] += __shfl_xor(acc[m], 16);
        acc[m] += __shfl_xor(acc[m], 32);
    }
    if (ksLo == 0) {
        #pragma unroll
        for (int m = 0; m < 4; ++m)
            part[(ksHi * TT + ig * 4 + m) * PSTR + jg] = acc[m];
    }
    __syncthreads();

    // ================= softmax (rows) -> 2D cumsum -> Pm =================
    if (tid < 256) {
        const int i = tid >> 4, j = tid & 15;
        float s = 0.f;
        #pragma unroll
        for (int kh = 0; kh < 4; ++kh) s += part[(kh * TT + i) * PSTR + j];
        s *= (1.0f / sqrtf((float)CC));
        float mx = s;
        #pragma unroll
        for (int d = 1; d < 16; d <<= 1) mx = fmaxf(mx, __shfl_xor(mx, d));
        const float e = expf(s - mx);
        float sm = e;
        #pragma unroll
        for (int d = 1; d < 16; d <<= 1) sm += __shfl_xor(sm, d);
        Pm[i * PSTR + j] = e / sm;
    }
    __syncthreads();
    if (tid < TT) {   // cumsum over rows (per column)
        float run = 0.f;
        for (int r = 0; r < TT; ++r) { run += Pm[r * PSTR + tid]; Pm[r * PSTR + tid] = run; }
    }
    __syncthreads();
    if (tid < TT) {   // cumsum over cols (per row)
        float run = 0.f;
        for (int c = 0; c < TT; ++c) { run += Pm[tid * PSTR + c]; Pm[tid * PSTR + c] = run; }
    }
    __syncthreads();

    // ================= DP precompute: step-invariant q[aa][bb] =================
    // thread = (pair, ksD): pair = i*16+j, ksD picks a = ksD + 4*aa
    const int pair = tid >> 2;
    const int ksD  = tid & 3;
    const int i    = pair >> 4;
    const int j    = pair & 15;

    const float pij = Pm[i * PSTR + j];
    float cb[TT], rjv[TT];
    #pragma unroll
    for (int bb = 0; bb < TT; ++bb) {
        cb[bb] = pij - Pm[i * PSTR + bb] + (bb < j ? 0.0f : NEGV);
        int d2 = j - bb; if (d2 < 1) d2 = 1;
        rjv[bb] = rsqrtf((float)d2);
    }
    float q[4][TT];
    #pragma unroll
    for (int aa = 0; aa < 4; ++aa) {
        const int a = ksD + aa * 4;
        const float caa = -Pm[a * PSTR + j] + (a < i ? 0.0f : NEGV);
        int d1 = i - a; if (d1 < 1) d1 = 1;
        const float raa = rsqrtf((float)d1);
        #pragma unroll
        for (int bb = 0; bb < TT; ++bb) {
            q[aa][bb] = (caa + cb[bb] + Pm[a * PSTR + bb]) * (raa * rjv[bb]);
        }
    }

    const float D0 = pij / (float)((i + 1) * (j + 1));
    if (ksD == 0) Dm[i * DSTR + j] = D0;
    if (tid == 1020) fin[0] = D0;      // pair 255, ksD 0
    __syncthreads();

    // ================= DP: 15 steps, 2 ops/candidate =================
    for (int k = 1; k < TT; ++k) {
        const float* Dold = Dm + ((k - 1) & 1) * (TT * DSTR);
        float*       Dnew = Dm + (k & 1)       * (TT * DSTR);
        float m0 = -3.0e38f, m1 = -3.0e38f, m2 = -3.0e38f, m3 = -3.0e38f;
        #pragma unroll
        for (int aa = 0; aa < 4; ++aa) {
            const float* drow = Dold + (ksD + aa * 4) * DSTR;
            float4 d0 = *(const float4*)(drow + 0);
            float4 d1 = *(const float4*)(drow + 4);
            float4 d2 = *(const float4*)(drow + 8);
            float4 d3 = *(const float4*)(drow + 12);
            m0 = fmaxf(m0, q[aa][0]  + d0.x);
            m1 = fmaxf(m1, q[aa][1]  + d0.y);
            m2 = fmaxf(m2, q[aa][2]  + d0.z);
            m3 = fmaxf(m3, q[aa][3]  + d0.w);
            m0 = fmaxf(m0, q[aa][4]  + d1.x);
            m1 = fmaxf(m1, q[aa][5]  + d1.y);
            m2 = fmaxf(m2, q[aa][6]  + d1.z);
            m3 = fmaxf(m3, q[aa][7]  + d1.w);
            m0 = fmaxf(m0, q[aa][8]  + d2.x);
            m1 = fmaxf(m1, q[aa][9]  + d2.y);
            m2 = fmaxf(m2, q[aa][10] + d2.z);
            m3 = fmaxf(m3, q[aa][11] + d2.w);
            m0 = fmaxf(m0, q[aa][12] + d3.x);
            m1 = fmaxf(m1, q[aa][13] + d3.y);
            m2 = fmaxf(m2, q[aa][14] + d3.z);
            m3 = fmaxf(m3, q[aa][15] + d3.w);
        }
        float m = fmaxf(fmaxf(m0, m1), fmaxf(m2, m3));
        m = fmaxf(m, __shfl_xor(m, 1));   // reduce over ksD
        m = fmaxf(m, __shfl_xor(m, 2));
        if (ksD == 0) Dnew[i * DSTR + j] = m;
        if (tid == 1020) fin[k] = m;
        __syncthreads();
    }

    // ================= finalize =================
    if (tid == 0) {
        float best = fin[0];
        int   idx  = 0;
        #pragma unroll
        for (int k = 1; k < TT; ++k) {
            if (fin[k] > best) { best = fin[k]; idx = k; }
        }
        out[b]     = -best;
        out[B + b] = (float)idx;
    }
}

extern "C" void kernel_launch(void* const* d_in, const int* in_sizes, int n_in,
                              void* d_out, int out_size, void* d_ws, size_t ws_size,
                              hipStream_t stream)
{
    const float* f1 = (const float*)d_in[0];
    const float* f2 = (const float*)d_in[1];
    float* out = (float*)d_out;
    const int B = in_sizes[0] / (TT * CC);   // 256
    hipLaunchKernelGGL(cpa_kernel, dim3(B), dim3(1024), 0, stream, f1, f2, out, B);
}

// Round 3
// 33.283 us; speedup vs baseline: 4.6490x; 1.1090x over previous
//
#include <hip/hip_runtime.h>
#include <math.h>

#define TT 16
#define CC 2048
#define NEGV -1.0e30f
#define CW 256              // GEMM chunk width (floats)
#define NCK (CC / CW)       // 8 chunks
#define ASTR 260            // A/B LDS row stride (floats)
#define PSTR 17
#define DSTR 20

#define KEEP(x) asm volatile("" : "+v"(x))

// DPP rotate within each 16-lane row: dst lane j <- src lane (j-n)&15 (HW dir
// doesn't matter for correctness: masks are derived by rotating the lane id).
#define RORF(dst, src, n)                                                      \
    dst = __int_as_float(__builtin_amdgcn_update_dpp(                          \
        0, __float_as_int(src), 0x120 + (n), 0xF, 0xF, false))

__global__ __launch_bounds__(1024, 1) void cpa_kernel(
    const float* __restrict__ f1, const float* __restrict__ f2,
    float* __restrict__ out, int B)
{
    __shared__ float  As[TT * ASTR];
    __shared__ float  Bs[TT * ASTR];
    __shared__ float4 part4[256];
    __shared__ float  Pm[TT * PSTR];
    __shared__ float  Dm[2 * TT * DSTR];
    __shared__ float  fin[TT];

    const int b    = blockIdx.x;
    const int tid  = threadIdx.x;
    const int wv   = tid >> 6;
    const int lane = tid & 63;

    // ================= GEMM: wave (ti,tj) owns a 4x4 output tile =================
    const int ti = wv >> 2, tj = wv & 3;
    const float* baseA = f1 + (size_t)b * TT * CC;
    const float* baseB = f2 + (size_t)b * TT * CC;

    float acc[4][4] = {};
    float4 av = *(const float4*)(baseA + wv * CC + lane * 4);
    float4 bv = *(const float4*)(baseB + wv * CC + lane * 4);

    for (int ck = 0; ck < NCK; ++ck) {
        *(float4*)&As[wv * ASTR + lane * 4] = av;
        *(float4*)&Bs[wv * ASTR + lane * 4] = bv;
        __syncthreads();
        if (ck + 1 < NCK) {
            av = *(const float4*)(baseA + wv * CC + (ck + 1) * CW + lane * 4);
            bv = *(const float4*)(baseB + wv * CC + (ck + 1) * CW + lane * 4);
        }
        float4 am[4], bn[4];
        #pragma unroll
        for (int m = 0; m < 4; ++m)
            am[m] = *(const float4*)&As[(ti * 4 + m) * ASTR + lane * 4];
        #pragma unroll
        for (int n = 0; n < 4; ++n)
            bn[n] = *(const float4*)&Bs[(tj * 4 + n) * ASTR + lane * 4];
        #pragma unroll
        for (int m = 0; m < 4; ++m) {
            #pragma unroll
            for (int n = 0; n < 4; ++n) {
                acc[m][n] = fmaf(am[m].x, bn[n].x, acc[m][n]);
                acc[m][n] = fmaf(am[m].y, bn[n].y, acc[m][n]);
                acc[m][n] = fmaf(am[m].z, bn[n].z, acc[m][n]);
                acc[m][n] = fmaf(am[m].w, bn[n].w, acc[m][n]);
            }
        }
        __syncthreads();
    }
    // in-wave K-reduce over each 16-lane group via DPP rotations (VALU pipe)
    #pragma unroll
    for (int m = 0; m < 4; ++m) {
        #pragma unroll
        for (int n = 0; n < 4; ++n) {
            float v = acc[m][n], t;
            RORF(t, v, 1); v += t;
            RORF(t, v, 2); v += t;
            RORF(t, v, 4); v += t;
            RORF(t, v, 8); v += t;
            if ((lane & 15) == 0)   // one writer per 16-lane group
                ((float*)&part4[(ti * 4 + m) * 16 + (tj * 4 + n)])[lane >> 4] = v;
        }
    }
    __syncthreads();

    // ================= softmax (rows) =================
    if (tid < 256) {
        const int si = tid >> 4, sj = tid & 15;
        float4 p = part4[tid];
        float s = (p.x + p.y + p.z + p.w) * (1.0f / sqrtf((float)CC));
        float mx = s;
        #pragma unroll
        for (int d = 1; d < 16; d <<= 1) mx = fmaxf(mx, __shfl_xor(mx, d));
        const float e = expf(s - mx);
        float sm = e;
        #pragma unroll
        for (int d = 1; d < 16; d <<= 1) sm += __shfl_xor(sm, d);
        Pm[si * PSTR + sj] = e / sm;
    }
    __syncthreads();
    if (tid < TT) {   // cumsum over rows (per column)
        float run = 0.f;
        for (int r = 0; r < TT; ++r) { run += Pm[r * PSTR + tid]; Pm[r * PSTR + tid] = run; }
    }
    __syncthreads();
    if (tid < TT) {   // cumsum over cols (per row)
        float run = 0.f;
        for (int c = 0; c < TT; ++c) { run += Pm[tid * PSTR + c]; Pm[tid * PSTR + c] = run; }
    }
    __syncthreads();

    // ================= DP precompute (DPP-rotation based) =================
    // wave -> output row i (balanced so each SIMD gets equal masked work)
    const int i_dp = (int)((0x612073458ABC9DEFull >> (4 * wv)) & 15);
    const int ksD  = lane >> 4;
    const int j    = lane & 15;
    const float jf = (float)j;

    const float pij = Pm[i_dp * PSTR + j];
    float vA0 = Pm[(ksD +  0) * PSTR + j];
    float vA1 = Pm[(ksD +  4) * PSTR + j];
    float vA2 = Pm[(ksD +  8) * PSTR + j];
    float vA3 = Pm[(ksD + 12) * PSTR + j];
    float ca0, ca1, ca2, ca3, ra0, ra1, ra2, ra3;
    {
        int a, d1;
        a = ksD;      ca0 = -vA0 + (a < i_dp ? 0.f : NEGV); d1 = i_dp - a; if (d1 < 1) d1 = 1; ra0 = rsqrtf((float)d1);
        a = ksD + 4;  ca1 = -vA1 + (a < i_dp ? 0.f : NEGV); d1 = i_dp - a; if (d1 < 1) d1 = 1; ra1 = rsqrtf((float)d1);
        a = ksD + 8;  ca2 = -vA2 + (a < i_dp ? 0.f : NEGV); d1 = i_dp - a; if (d1 < 1) d1 = 1; ra2 = rsqrtf((float)d1);
        a = ksD + 12; ca3 = -vA3 + (a < i_dp ? 0.f : NEGV); d1 = i_dp - a; if (d1 < 1) d1 = 1; ra3 = rsqrtf((float)d1);
    }

    float qr[4][16];
    // t = 0: bb == j -> masked; area clamp -> rjt = 1
    qr[0][0] = (ca0 + NEGV + vA0) * ra0; KEEP(qr[0][0]);
    qr[1][0] = (ca1 + NEGV + vA1) * ra1; KEEP(qr[1][0]);
    qr[2][0] = (ca2 + NEGV + vA2) * ra2; KEEP(qr[2][0]);
    qr[3][0] = (ca3 + NEGV + vA3) * ra3; KEEP(qr[3][0]);

#define QSTEP(n)                                                               \
    {                                                                          \
        float bbf, rIt, rAt;                                                   \
        RORF(bbf, jf, n);                                                      \
        RORF(rIt, pij, n);                                                     \
        const int bbi = (int)bbf;                                              \
        int d2 = j - bbi; if (d2 < 1) d2 = 1;                                  \
        const float rjt = rsqrtf((float)d2);                                   \
        const float cbm = pij - rIt + ((bbi < j) ? 0.0f : NEGV);               \
        RORF(rAt, vA0, n); qr[0][n] = (ca0 + cbm + rAt) * (ra0 * rjt); KEEP(qr[0][n]); \
        RORF(rAt, vA1, n); qr[1][n] = (ca1 + cbm + rAt) * (ra1 * rjt); KEEP(qr[1][n]); \
        RORF(rAt, vA2, n); qr[2][n] = (ca2 + cbm + rAt) * (ra2 * rjt); KEEP(qr[2][n]); \
        RORF(rAt, vA3, n); qr[3][n] = (ca3 + cbm + rAt) * (ra3 * rjt); KEEP(qr[3][n]); \
    }
    QSTEP(1)  QSTEP(2)  QSTEP(3)  QSTEP(4)  QSTEP(5)  QSTEP(6)  QSTEP(7)
    QSTEP(8)  QSTEP(9)  QSTEP(10) QSTEP(11) QSTEP(12) QSTEP(13) QSTEP(14) QSTEP(15)
#undef QSTEP

    const float D0 = pij / (float)((i_dp + 1) * (j + 1));
    if (ksD == 0) Dm[i_dp * DSTR + j] = D0;
    if (wv == 0 && lane == 15) fin[0] = D0;   // imap[0]=15 -> (15,15)
    __syncthreads();

    // ================= DP: 15 steps, DPP-systolic =================
    const int nA = (i_dp + 3) >> 2;   // wave-uniform masked trip count

#define DSTEP(A_, n, MACC)                                                     \
    { float dt_; RORF(dt_, dbase, n); MACC = fmaxf(MACC, dt_ + qr[A_][n]); }
#define AABLOCK(A_, DB_)                                                       \
    if (A_ < nA) {                                                             \
        const float dbase = DB_;                                               \
        m0 = fmaxf(m0, dbase + qr[A_][0]);                                     \
        DSTEP(A_, 1, m1)  DSTEP(A_, 2, m2)  DSTEP(A_, 3, m3)  DSTEP(A_, 4, m0) \
        DSTEP(A_, 5, m1)  DSTEP(A_, 6, m2)  DSTEP(A_, 7, m3)  DSTEP(A_, 8, m0) \
        DSTEP(A_, 9, m1)  DSTEP(A_, 10, m2) DSTEP(A_, 11, m3) DSTEP(A_, 12, m0)\
        DSTEP(A_, 13, m1) DSTEP(A_, 14, m2) DSTEP(A_, 15, m3)                  \
    }

    for (int k = 1; k < TT; ++k) {
        const float* Dold = Dm + ((k - 1) & 1) * (TT * DSTR);
        float*       Dnew = Dm + (k & 1)       * (TT * DSTR);
        // coalesced row loads (rows always in-bounds; garbage rows lose the max)
        const float d0_0 = Dold[(ksD +  0) * DSTR + j];
        const float d0_1 = Dold[(ksD +  4) * DSTR + j];
        const float d0_2 = Dold[(ksD +  8) * DSTR + j];
        const float d0_3 = Dold[(ksD + 12) * DSTR + j];
        float m0 = -3.0e38f, m1 = -3.0e38f, m2 = -3.0e38f, m3 = -3.0e38f;
        AABLOCK(0, d0_0)
        AABLOCK(1, d0_1)
        AABLOCK(2, d0_2)
        AABLOCK(3, d0_3)
        float mm = fmaxf(fmaxf(m0, m1), fmaxf(m2, m3));
        mm = fmaxf(mm, __shfl_xor(mm, 16));
        mm = fmaxf(mm, __shfl_xor(mm, 32));
        if (ksD == 0) Dnew[i_dp * DSTR + j] = mm;
        if (wv == 0 && lane == 15) fin[k] = mm;
        __syncthreads();
    }
#undef AABLOCK
#undef DSTEP

    // ================= finalize =================
    if (tid == 0) {
        float best = fin[0];
        int   idx  = 0;
        #pragma unroll
        for (int k = 1; k < TT; ++k) {
            if (fin[k] > best) { best = fin[k]; idx = k; }
        }
        out[b]     = -best;
        out[B + b] = (float)idx;
    }
}

extern "C" void kernel_launch(void* const* d_in, const int* in_sizes, int n_in,
                              void* d_out, int out_size, void* d_ws, size_t ws_size,
                              hipStream_t stream)
{
    const float* f1 = (const float*)d_in[0];
    const float* f2 = (const float*)d_in[1];
    float* out = (float*)d_out;
    const int B = in_sizes[0] / (TT * CC);   // 256
    hipLaunchKernelGGL(cpa_kernel, dim3(B), dim3(1024), 0, stream, f1, f2, out, B);
}

// Round 5
// 30.497 us; speedup vs baseline: 5.0738x; 1.0914x over previous
//
#include <hip/hip_runtime.h>
#include <math.h>

#define TT 16
#define CC 2048
#define NEGV -1.0e30f
#define CW 256              // GEMM chunk width (floats)
#define NCK (CC / CW)       // 8 chunks
#define ASTR 260            // A/B LDS row stride (floats)
#define PSTR 48             // Pm row stride: 4-row strided reads -> 2-way (free)
#define DSTR 48             // Dm row stride: same

#define KEEP(x) asm volatile("" : "+v"(x))

// DPP rotate within each 16-lane row: dst lane j <- src lane (j-n)&15 (HW dir
// doesn't matter for correctness: masks are derived by rotating the lane id).
#define RORF(dst, src, n)                                                      \
    dst = __int_as_float(__builtin_amdgcn_update_dpp(                          \
        0, __float_as_int(src), 0x120 + (n), 0xF, 0xF, false))

__global__ __launch_bounds__(1024, 1) void cpa_kernel(
    const float* __restrict__ f1, const float* __restrict__ f2,
    float* __restrict__ out, int B)
{
    __shared__ float  As[TT * ASTR];
    __shared__ float  Bs[TT * ASTR];
    __shared__ float4 part4[256];
    __shared__ float  Pm[TT * PSTR];
    __shared__ float  Dm[2 * TT * DSTR];
    __shared__ float  fin[TT];

    const int b    = blockIdx.x;
    const int tid  = threadIdx.x;
    const int wv   = tid >> 6;
    const int lane = tid & 63;

    // ================= GEMM: wave (ti,tj) owns a 4x4 output tile =================
    const int ti = wv >> 2, tj = wv & 3;
    const float* baseA = f1 + (size_t)b * TT * CC;
    const float* baseB = f2 + (size_t)b * TT * CC;

    float acc[4][4] = {};
    float4 av = *(const float4*)(baseA + wv * CC + lane * 4);
    float4 bv = *(const float4*)(baseB + wv * CC + lane * 4);

    for (int ck = 0; ck < NCK; ++ck) {
        *(float4*)&As[wv * ASTR + lane * 4] = av;
        *(float4*)&Bs[wv * ASTR + lane * 4] = bv;
        __syncthreads();
        if (ck + 1 < NCK) {
            av = *(const float4*)(baseA + wv * CC + (ck + 1) * CW + lane * 4);
            bv = *(const float4*)(baseB + wv * CC + (ck + 1) * CW + lane * 4);
        }
        float4 am[4], bn[4];
        #pragma unroll
        for (int m = 0; m < 4; ++m)
            am[m] = *(const float4*)&As[(ti * 4 + m) * ASTR + lane * 4];
        #pragma unroll
        for (int n = 0; n < 4; ++n)
            bn[n] = *(const float4*)&Bs[(tj * 4 + n) * ASTR + lane * 4];
        #pragma unroll
        for (int m = 0; m < 4; ++m) {
            #pragma unroll
            for (int n = 0; n < 4; ++n) {
                acc[m][n] = fmaf(am[m].x, bn[n].x, acc[m][n]);
                acc[m][n] = fmaf(am[m].y, bn[n].y, acc[m][n]);
                acc[m][n] = fmaf(am[m].z, bn[n].z, acc[m][n]);
                acc[m][n] = fmaf(am[m].w, bn[n].w, acc[m][n]);
            }
        }
        __syncthreads();
    }
    // in-wave K-reduce over each 16-lane group via DPP rotations (VALU pipe)
    #pragma unroll
    for (int m = 0; m < 4; ++m) {
        #pragma unroll
        for (int n = 0; n < 4; ++n) {
            float v = acc[m][n], t;
            RORF(t, v, 1); v += t;
            RORF(t, v, 2); v += t;
            RORF(t, v, 4); v += t;
            RORF(t, v, 8); v += t;
            if ((lane & 15) == 0)   // one writer per 16-lane group
                ((float*)&part4[(ti * 4 + m) * 16 + (tj * 4 + n)])[lane >> 4] = v;
        }
    }
    __syncthreads();

    // ================= softmax (rows) =================
    if (tid < 256) {
        const int si = tid >> 4, sj = tid & 15;
        float4 p = part4[tid];
        float s = (p.x + p.y + p.z + p.w) * (1.0f / sqrtf((float)CC));
        float mx = s;
        #pragma unroll
        for (int d = 1; d < 16; d <<= 1) mx = fmaxf(mx, __shfl_xor(mx, d));
        const float e = expf(s - mx);
        float sm = e;
        #pragma unroll
        for (int d = 1; d < 16; d <<= 1) sm += __shfl_xor(sm, d);
        Pm[si * PSTR + sj] = e / sm;
    }
    __syncthreads();

    // ======= 2D cumsum: SERIAL, numpy summation order (bit-exactness is =======
    // ======= load-bearing: DP increments tie at exactly 0.0; argmax is  =======
    // ======= first-occurrence, so P must not be reassociated)           =======
    if (tid < TT) {   // cumsum over rows (per column)
        float run = 0.f;
        for (int r = 0; r < TT; ++r) { run += Pm[r * PSTR + tid]; Pm[r * PSTR + tid] = run; }
    }
    __syncthreads();
    if (tid < TT) {   // cumsum over cols (per row)
        float run = 0.f;
        for (int c = 0; c < TT; ++c) { run += Pm[tid * PSTR + c]; Pm[tid * PSTR + c] = run; }
    }
    __syncthreads();

    // ================= DP precompute (DPP-rotation based) =================
    // wave -> output row i (balanced so each SIMD gets equal masked work)
    const int i_dp = (int)((0x612073458ABC9DEFull >> (4 * wv)) & 15);
    const int ksD  = lane >> 4;
    const int j    = lane & 15;
    const float jf = (float)j;

    const float pij = Pm[i_dp * PSTR + j];
    float vA0 = Pm[(ksD +  0) * PSTR + j];
    float vA1 = Pm[(ksD +  4) * PSTR + j];
    float vA2 = Pm[(ksD +  8) * PSTR + j];
    float vA3 = Pm[(ksD + 12) * PSTR + j];
    float ca0, ca1, ca2, ca3, ra0, ra1, ra2, ra3;
    {
        int a, d1;
        a = ksD;      ca0 = -vA0 + (a < i_dp ? 0.f : NEGV); d1 = i_dp - a; if (d1 < 1) d1 = 1; ra0 = rsqrtf((float)d1);
        a = ksD + 4;  ca1 = -vA1 + (a < i_dp ? 0.f : NEGV); d1 = i_dp - a; if (d1 < 1) d1 = 1; ra1 = rsqrtf((float)d1);
        a = ksD + 8;  ca2 = -vA2 + (a < i_dp ? 0.f : NEGV); d1 = i_dp - a; if (d1 < 1) d1 = 1; ra2 = rsqrtf((float)d1);
        a = ksD + 12; ca3 = -vA3 + (a < i_dp ? 0.f : NEGV); d1 = i_dp - a; if (d1 < 1) d1 = 1; ra3 = rsqrtf((float)d1);
    }

    float qr[4][16];
    // t = 0: bb == j -> masked; area clamp -> rjt = 1
    qr[0][0] = (ca0 + NEGV + vA0) * ra0; KEEP(qr[0][0]);
    qr[1][0] = (ca1 + NEGV + vA1) * ra1; KEEP(qr[1][0]);
    qr[2][0] = (ca2 + NEGV + vA2) * ra2; KEEP(qr[2][0]);
    qr[3][0] = (ca3 + NEGV + vA3) * ra3; KEEP(qr[3][0]);

#define QSTEP(n)                                                               \
    {                                                                          \
        float bbf, rIt, rAt;                                                   \
        RORF(bbf, jf, n);                                                      \
        RORF(rIt, pij, n);                                                     \
        const int bbi = (int)bbf;                                              \
        int d2 = j - bbi; if (d2 < 1) d2 = 1;                                  \
        const float rjt = rsqrtf((float)d2);                                   \
        const float cbm = pij - rIt + ((bbi < j) ? 0.0f : NEGV);               \
        RORF(rAt, vA0, n); qr[0][n] = (ca0 + cbm + rAt) * (ra0 * rjt); KEEP(qr[0][n]); \
        RORF(rAt, vA1, n); qr[1][n] = (ca1 + cbm + rAt) * (ra1 * rjt); KEEP(qr[1][n]); \
        RORF(rAt, vA2, n); qr[2][n] = (ca2 + cbm + rAt) * (ra2 * rjt); KEEP(qr[2][n]); \
        RORF(rAt, vA3, n); qr[3][n] = (ca3 + cbm + rAt) * (ra3 * rjt); KEEP(qr[3][n]); \
    }
    QSTEP(1)  QSTEP(2)  QSTEP(3)  QSTEP(4)  QSTEP(5)  QSTEP(6)  QSTEP(7)
    QSTEP(8)  QSTEP(9)  QSTEP(10) QSTEP(11) QSTEP(12) QSTEP(13) QSTEP(14) QSTEP(15)
#undef QSTEP

    const float D0 = pij / (float)((i_dp + 1) * (j + 1));
    if (ksD == 0) Dm[i_dp * DSTR + j] = D0;
    if (wv == 0 && lane == 15) fin[0] = D0;   // imap[0]=15 -> (15,15)
    __syncthreads();

    // ================= DP: 15 steps, DPP-systolic, k-windowed =================
    // D_k(i,j) only reachable for i,j >= k; candidates only a in [k-1, i).
    // Windowed-out candidates (a <= k-2) have garbage D_{k-1} <= -1e29 and can
    // never win the max; fmaxf reordering is exact, so fin[] is bit-identical
    // to the unwindowed version.
    const int nA = (i_dp + 3) >> 2;   // wave-uniform masked trip count

#define DSTEP(A_, n, MACC)                                                     \
    { float dt_; RORF(dt_, dbase, n); MACC = fmaxf(MACC, dt_ + qr[A_][n]); }
#define AABLOCK(A_, TLO_)                                                      \
    if (A_ >= (TLO_) && A_ < nA) {                                             \
        const float dbase = Dold[(ksD + A_ * 4) * DSTR + j];                   \
        m0 = fmaxf(m0, dbase + qr[A_][0]);                                     \
        DSTEP(A_, 1, m1)  DSTEP(A_, 2, m2)  DSTEP(A_, 3, m3)  DSTEP(A_, 4, m0) \
        DSTEP(A_, 5, m1)  DSTEP(A_, 6, m2)  DSTEP(A_, 7, m3)  DSTEP(A_, 8, m0) \
        DSTEP(A_, 9, m1)  DSTEP(A_, 10, m2) DSTEP(A_, 11, m3) DSTEP(A_, 12, m0)\
        DSTEP(A_, 13, m1) DSTEP(A_, 14, m2) DSTEP(A_, 15, m3)                  \
    }

    #pragma unroll
    for (int k = 1; k < TT; ++k) {
        const float* Dold = Dm + ((k - 1) & 1) * (TT * DSTR);
        float*       Dnew = Dm + (k & 1)       * (TT * DSTR);
        if (i_dp >= k) {
            const int tlo = (k - 1) >> 2;     // compile-time after unroll
            float m0 = -3.0e38f, m1 = -3.0e38f, m2 = -3.0e38f, m3 = -3.0e38f;
            AABLOCK(0, tlo)
            AABLOCK(1, tlo)
            AABLOCK(2, tlo)
            AABLOCK(3, tlo)
            float mm = fmaxf(fmaxf(m0, m1), fmaxf(m2, m3));
            mm = fmaxf(mm, __shfl_xor(mm, 16));
            mm = fmaxf(mm, __shfl_xor(mm, 32));
            if (ksD == 0) Dnew[i_dp * DSTR + j] = mm;
            if (wv == 0 && lane == 15) fin[k] = mm;
        } else if (ksD == 0) {
            Dnew[i_dp * DSTR + j] = -3.0e38f;  // retired row: garbage, never wins
        }
        __syncthreads();
    }
#undef AABLOCK
#undef DSTEP

    // ================= finalize: serial first-occurrence argmax =================
    if (tid == 0) {
        float best = fin[0];
        int   idx  = 0;
        #pragma unroll
        for (int k = 1; k < TT; ++k) {
            if (fin[k] > best) { best = fin[k]; idx = k; }
        }
        out[b]     = -best;
        out[B + b] = (float)idx;
    }
}

extern "C" void kernel_launch(void* const* d_in, const int* in_sizes, int n_in,
                              void* d_out, int out_size, void* d_ws, size_t ws_size,
                              hipStream_t stream)
{
    const float* f1 = (const float*)d_in[0];
    const float* f2 = (const float*)d_in[1];
    float* out = (float*)d_out;
    const int B = in_sizes[0] / (TT * CC);   // 256
    hipLaunchKernelGGL(cpa_kernel, dim3(B), dim3(1024), 0, stream, f1, f2, out, B);
}